// Round 3
// baseline (624.069 us; speedup 1.0000x reference)
//
#include <hip/hip_runtime.h>
#include <math.h>

// Problem constants
#define BB   4
#define CC   128
#define HH   64
#define WW   64
#define OUTC 128
#define KK   25   // 5x5 attention taps
#define PXB  16   // pixels per block (quarter row)

typedef __attribute__((ext_vector_type(8))) short short8;   // 8 bf16
typedef __attribute__((ext_vector_type(4))) float floatx4;  // MFMA acc

__device__ __forceinline__ unsigned short f32_to_bf16(float v) {
    unsigned int u = __float_as_uint(v);
    u += 0x7fffu + ((u >> 16) & 1u);          // RNE
    return (unsigned short)(u >> 16);
}

// ---------------------------------------------------------------------------
// Kernel 0 (prep):
//  i < 16384:  w2o[o][c] = bf16( sum_r w2[o, c*4+r] )        (o-major)
//  else:       w1tp[c][kk][12] = w1[kk][c][0..8] (pad 9..11): per-tap reads
//              are two aligned float4 + one dword (VMEM, deep pipelining).
// ---------------------------------------------------------------------------
__global__ void prep_kernel(const float* __restrict__ w2,
                            const float* __restrict__ w1,
                            unsigned short* __restrict__ w2o,
                            float* __restrict__ w1tp) {
    int i = blockIdx.x * 256 + threadIdx.x;
    if (i < 16384) {
        int o = i >> 7, c = i & 127;
        const float* p = w2 + o * (4 * CC) + c * 4;
        w2o[o * CC + c] = f32_to_bf16(p[0] + p[1] + p[2] + p[3]);
    } else if (i < 16384 + 38400) {
        int j   = i - 16384;
        int c   = j / 300;
        int rem = j - c * 300;
        int kk  = rem / 12;
        int jj  = rem - kk * 12;
        w1tp[j] = (jj < 9) ? w1[((size_t)kk * CC + c) * 9 + jj] : 0.f;
    }
}

// ---------------------------------------------------------------------------
// Fused kernel: conv1 (3x3) + softmax + local attention + MFMA + 2x2 store.
// grid 1024 = (b, h, wq): 16-px quarter-row per block, 256 threads (4 waves)
// -> exactly 4 blocks/CU (16 waves/CU) for latency hiding; VGPR capped 128.
//  conv1 : lane = (pp: 8 px-pairs, cl: 8 c-streams); wave wv owns channels
//          [32wv, 32wv+32), 4 ci per thread. 2 px per thread -> each weight
//          tap (9 dwords, 3 VMEM insts) feeds 18 FMA (2x the AI of v2).
//          Reduce: shfl_xor(8/16/32) butterfly + LDS atomics (8 lanes/wave).
//  softmax: in-register per phase-C thread (redundant, zero barriers).
//  phase C: x windows straight from L1/L2 (rows warm from conv).
//  MFMA  : C[128 o][16 px], wave wv owns o-rows [32wv,32wv+32).
// ---------------------------------------------------------------------------
__global__ __launch_bounds__(256, 4) void fused_kernel(
        const float* __restrict__ x,
        const float* __restrict__ w1tp,
        const unsigned short* __restrict__ w2o,
        const float* __restrict__ b1,
        const float* __restrict__ b2,
        float* __restrict__ out) {
    __shared__ float pk[KK * PXB];              // logits        (1.6 KB)
    __shared__ unsigned short sKT[PXB * 136];   // s bf16 [px][c] (4.25 KB)

    // XCD-aware swizzle (1024 % 8 == 0 -> bijective): 128 consecutive bids
    // per XCD -> same b, contiguous h -> x slice L2-resident per XCD.
    int bid0 = blockIdx.x;
    int bid  = (bid0 & 7) * 128 + (bid0 >> 3);
    int wq = bid & 3;
    int h  = (bid >> 2) & 63;
    int b  = bid >> 8;
    int t  = threadIdx.x;
    int lane = t & 63;
    int wv = __builtin_amdgcn_readfirstlane(t >> 6);   // 0..3

    // ---- init logits with conv1 bias ----
    for (int i = t; i < KK * PXB; i += 256) pk[i] = b1[i >> 4];
    __syncthreads();

    // ---- conv1 3x3 SAME: 2 px + 4 channels per thread ----
    int pp = lane & 7;                  // px pair within quarter
    int cl = lane >> 3;                 // c-stream 0..7
    int px0 = wq * 16 + 2 * pp;         // even global col
    int px1 = px0 + 1;

    float mt = (h > 0) ? 1.f : 0.f, mb = (h < HH - 1) ? 1.f : 0.f;
    float ml = (px0 > 0) ? 1.f : 0.f, mr = (px1 < WW - 1) ? 1.f : 0.f;
    int ya = (h > 0) ? h - 1 : 0;
    int yb = (h < HH - 1) ? h + 1 : HH - 1;
    int xl = (px0 > 0) ? px0 - 1 : 0;
    int xr = (px1 < WW - 1) ? px1 + 1 : WW - 1;

    float a0[KK], a1[KK];
    #pragma unroll
    for (int k = 0; k < KK; ++k) { a0[k] = 0.f; a1[k] = 0.f; }

    const float* xb = x + (size_t)b * CC * (HH * WW);
    int cbase = wv * 32 + cl * 4;
    const float* wb = w1tp + (size_t)cbase * 300;

    #pragma unroll 2
    for (int ci = 0; ci < 4; ++ci) {
        const float* xp = xb + (size_t)(cbase + ci) * (HH * WW);
        const float* r0 = xp + ya * WW;
        const float* r1 = xp + h  * WW;
        const float* r2 = xp + yb * WW;
        float2 v0 = *(const float2*)(r0 + px0);
        float2 v1 = *(const float2*)(r1 + px0);
        float2 v2 = *(const float2*)(r2 + px0);
        float l0 = r0[xl], l1 = r1[xl], l2 = r2[xl];
        float q0 = r0[xr], q1 = r1[xr], q2 = r2[xr];
        v0.x *= mt; v0.y *= mt; l0 *= mt * ml; q0 *= mt * mr;
        l1 *= ml; q1 *= mr;
        v2.x *= mb; v2.y *= mb; l2 *= mb * ml; q2 *= mb * mr;

        const float* wc = wb + ci * 300;
        #pragma unroll
        for (int kk = 0; kk < KK; ++kk) {
            float4 wA = *(const float4*)(wc + kk * 12);
            float4 wB = *(const float4*)(wc + kk * 12 + 4);
            float  w8 = wc[kk * 12 + 8];
            a0[kk] += l0   * wA.x + v0.x * wA.y + v0.y * wA.z
                    + l1   * wA.w + v1.x * wB.x + v1.y * wB.y
                    + l2   * wB.z + v2.x * wB.w + v2.y * w8;
            a1[kk] += v0.x * wA.x + v0.y * wA.y + q0   * wA.z
                    + v1.x * wA.w + v1.y * wB.x + q1   * wB.y
                    + v2.x * wB.z + v2.y * wB.w + q2   * w8;
        }
    }

    // butterfly over the 8 c-streams (lane bits 3,4,5)
    #pragma unroll
    for (int k = 0; k < KK; ++k) {
        a0[k] += __shfl_xor(a0[k], 8);  a1[k] += __shfl_xor(a1[k], 8);
        a0[k] += __shfl_xor(a0[k], 16); a1[k] += __shfl_xor(a1[k], 16);
        a0[k] += __shfl_xor(a0[k], 32); a1[k] += __shfl_xor(a1[k], 32);
    }
    if (cl == 0) {
        #pragma unroll
        for (int k = 0; k < KK; ++k) {
            atomicAdd(&pk[k * PXB + 2 * pp],     a0[k]);
            atomicAdd(&pk[k * PXB + 2 * pp + 1], a1[k]);
        }
    }
    __syncthreads();

    // ---- phase C: in-register softmax + attention straight from L2 ----
    // thread = (pp2 = t&7 -> px {2pp2, 2pp2+1}, cw = t>>3 -> 4 channels)
    int pp2 = t & 7, cw = t >> 3;

    float2 lg[KK];
    #pragma unroll
    for (int k = 0; k < KK; ++k) lg[k] = *(const float2*)&pk[k * PXB + 2 * pp2];
    float m0 = -1e30f, m1 = -1e30f;
    #pragma unroll
    for (int k = 0; k < KK; ++k) { m0 = fmaxf(m0, lg[k].x); m1 = fmaxf(m1, lg[k].y); }
    float s0 = 0.f, s1 = 0.f;
    #pragma unroll
    for (int k = 0; k < KK; ++k) {
        lg[k].x = __expf(lg[k].x - m0); s0 += lg[k].x;
        lg[k].y = __expf(lg[k].y - m1); s1 += lg[k].y;
    }
    float i0 = 1.f / s0, i1 = 1.f / s1;
    #pragma unroll
    for (int k = 0; k < KK; ++k) { lg[k].x *= i0; lg[k].y *= i1; }

    // window geometry: 5 rows x 3 float2 loads (all col offsets even ->
    // a float2 is either fully in-bounds or fully out -> single mask)
    int colg = wq * 16 + 2 * pp2 - 2;
    int coff[3]; float cmask[3];
    #pragma unroll
    for (int j = 0; j < 3; ++j) {
        int cg = colg + 2 * j;
        cmask[j] = (cg >= 0 && cg <= WW - 2) ? 1.f : 0.f;
        coff[j]  = min(max(cg, 0), WW - 2);
    }
    int yoff[5]; float msk[15];
    #pragma unroll
    for (int di = 0; di < 5; ++di) {
        int y = h + di - 2;
        float rm = (y >= 0 && y < HH) ? 1.f : 0.f;
        yoff[di] = min(max(y, 0), HH - 1) * WW;
        #pragma unroll
        for (int j = 0; j < 3; ++j) msk[di * 3 + j] = rm * cmask[j];
    }

    #pragma unroll 2
    for (int i4 = 0; i4 < 4; ++i4) {
        int c = i4 * 32 + cw;
        const float* xc = xb + (size_t)c * (HH * WW);
        float2 xv[15];
        #pragma unroll
        for (int di = 0; di < 5; ++di)
            #pragma unroll
            for (int j = 0; j < 3; ++j) {
                float2 v = *(const float2*)(xc + yoff[di] + coff[j]);
                float mm = msk[di * 3 + j];
                xv[di * 3 + j] = make_float2(v.x * mm, v.y * mm);
            }
        float t0 = 0.f, t1 = 0.f;
        #pragma unroll
        for (int di = 0; di < 5; ++di) {
            float2 x01 = xv[di * 3 + 0];
            float2 x23 = xv[di * 3 + 1];
            float2 x45 = xv[di * 3 + 2];
            t0 += lg[di*5+0].x * x01.x + lg[di*5+1].x * x01.y
                + lg[di*5+2].x * x23.x + lg[di*5+3].x * x23.y
                + lg[di*5+4].x * x45.x;
            t1 += lg[di*5+0].y * x01.y + lg[di*5+1].y * x23.x
                + lg[di*5+2].y * x23.y + lg[di*5+3].y * x45.x
                + lg[di*5+4].y * x45.y;
        }
        sKT[(2 * pp2) * 136 + c]     = f32_to_bf16(t0);
        sKT[(2 * pp2 + 1) * 136 + c] = f32_to_bf16(t1);
    }
    __syncthreads();

    // ---- MFMA: C[o][px] = sum_c W2s[o][c] * s[c][px] ----
    int fpx = lane & 15, quad = lane >> 4;
    floatx4 am[2] = {{0.f,0.f,0.f,0.f},{0.f,0.f,0.f,0.f}};
    #pragma unroll
    for (int ks = 0; ks < 4; ++ks) {
        short8 bf  = *(const short8*)&sKT[fpx * 136 + ks*32 + quad*8];
        short8 af0 = *(const short8*)&w2o[(size_t)(32*wv      + fpx) * CC + ks*32 + quad*8];
        short8 af1 = *(const short8*)&w2o[(size_t)(32*wv + 16 + fpx) * CC + ks*32 + quad*8];
        am[0] = __builtin_amdgcn_mfma_f32_16x16x32_bf16(af0, bf, am[0], 0, 0, 0);
        am[1] = __builtin_amdgcn_mfma_f32_16x16x32_bf16(af1, bf, am[1], 0, 0, 0);
    }

    // ---- epilogue: D[row=quad*4+reg][col=fpx] + b2, 2x2-replicated write ----
    float* ob = out + (size_t)b * OUTC * (4 * HH * WW);
    int y0 = 2 * h;
    int pxo = wq * 16 + fpx;
    #pragma unroll
    for (int mt2 = 0; mt2 < 2; ++mt2) {
        #pragma unroll
        for (int reg = 0; reg < 4; ++reg) {
            int o = 32*wv + 16*mt2 + quad*4 + reg;
            float v = am[mt2][reg] + b2[o];
            float2 v2 = make_float2(v, v);
            float* r0p = ob + ((size_t)o * (2*HH) + y0) * (2*WW) + 2*pxo;
            *(float2*)(r0p)        = v2;
            *(float2*)(r0p + 2*WW) = v2;
        }
    }
}

// ---------------------------------------------------------------------------
extern "C" void kernel_launch(void* const* d_in, const int* in_sizes, int n_in,
                              void* d_out, int out_size, void* d_ws, size_t ws_size,
                              hipStream_t stream) {
    const float* x  = (const float*)d_in[0];
    const float* w1 = (const float*)d_in[1];
    const float* b1 = (const float*)d_in[2];
    const float* w2 = (const float*)d_in[3];
    const float* b2 = (const float*)d_in[4];
    float* out = (float*)d_out;

    unsigned short* w2o = (unsigned short*)d_ws;               // 32 KB
    float* w1tp = (float*)(w2o + (size_t)OUTC * CC);           // 153.6 KB

    prep_kernel<<<(16384 + 38400 + 255) / 256, 256, 0, stream>>>(w2, w1, w2o, w1tp);
    fused_kernel<<<BB * HH * 4 * 4 / 4, 256, 0, stream>>>(x, w1tp, w2o, b1, b2, out);
}

// Round 4
// 146.400 us; speedup vs baseline: 4.2628x; 4.2628x over previous
//
#include <hip/hip_runtime.h>
#include <math.h>

// Problem constants
#define BB   4
#define CC   128
#define HH   64
#define WW   64
#define OUTC 128
#define KK   25   // 5x5 attention taps
#define PXB  16   // pixels per block (quarter row)

typedef __attribute__((ext_vector_type(8))) short short8;   // 8 bf16
typedef __attribute__((ext_vector_type(4))) float floatx4;  // MFMA acc

__device__ __forceinline__ unsigned short f32_to_bf16(float v) {
    unsigned int u = __float_as_uint(v);
    u += 0x7fffu + ((u >> 16) & 1u);          // RNE
    return (unsigned short)(u >> 16);
}

// ---------------------------------------------------------------------------
// Kernel 0 (prep):
//  i < 16384:  w2o[o][c] = bf16( sum_r w2[o, c*4+r] )        (o-major)
//  else:       w1tp[c][kk][12] = w1[kk][c][0..8] (pad 9..11): per-tap reads
//              are two aligned float4 + one dword (VMEM, deep pipelining).
// ---------------------------------------------------------------------------
__global__ void prep_kernel(const float* __restrict__ w2,
                            const float* __restrict__ w1,
                            unsigned short* __restrict__ w2o,
                            float* __restrict__ w1tp) {
    int i = blockIdx.x * 256 + threadIdx.x;
    if (i < 16384) {
        int o = i >> 7, c = i & 127;
        const float* p = w2 + o * (4 * CC) + c * 4;
        w2o[o * CC + c] = f32_to_bf16(p[0] + p[1] + p[2] + p[3]);
    } else if (i < 16384 + 38400) {
        int j   = i - 16384;
        int c   = j / 300;
        int rem = j - c * 300;
        int kk  = rem / 12;
        int jj  = rem - kk * 12;
        w1tp[j] = (jj < 9) ? w1[((size_t)kk * CC + c) * 9 + jj] : 0.f;
    }
}

// ---------------------------------------------------------------------------
// Fused kernel: conv1 (3x3) + softmax + local attention + MFMA + 2x2 store.
// grid 1024 = (b, h, wq): 16-px quarter-row per block, 256 threads (4 waves)
// -> 4 blocks/CU resident (16 waves/CU) PROVIDED VGPR <= 128.
// __launch_bounds__(256,2): cap 256 so the allocator does NOT spill the
// accumulator arrays (round-3 lesson: (256,4) forced VGPR=64 + 1.7 GB of
// scratch traffic -> 565 us). Natural allocation ~110-120 VGPR <= 128
// still yields 4 waves/SIMD in hardware.
//  conv1 : 1 px/thread (25 accs). lane=(16 px, 4 c-streams), 4 waves ->
//          16 streams x 8 channels. Weights per-lane VMEM float4 from the
//          padded layout. Reduce: shfl_xor(16/32) + 4-wave LDS atomics.
//  softmax: in-register per phase-C thread (redundant, zero barriers).
//  phase C: x windows straight from L1/L2 (rows warm from conv).
//  MFMA  : C[128 o][16 px], wave wv owns o-rows [32wv,32wv+32).
// ---------------------------------------------------------------------------
__global__ __launch_bounds__(256, 2) void fused_kernel(
        const float* __restrict__ x,
        const float* __restrict__ w1tp,
        const unsigned short* __restrict__ w2o,
        const float* __restrict__ b1,
        const float* __restrict__ b2,
        float* __restrict__ out) {
    __shared__ float pk[KK * PXB];              // logits        (1.6 KB)
    __shared__ unsigned short sKT[PXB * 136];   // s bf16 [px][c] (4.25 KB)

    // XCD-aware swizzle (1024 % 8 == 0 -> bijective): 128 consecutive bids
    // per XCD -> same b, contiguous h -> x slice L2-resident per XCD.
    int bid0 = blockIdx.x;
    int bid  = (bid0 & 7) * 128 + (bid0 >> 3);
    int wq = bid & 3;
    int h  = (bid >> 2) & 63;
    int b  = bid >> 8;
    int t  = threadIdx.x;
    int lane = t & 63;

    // ---- init logits with conv1 bias ----
    for (int i = t; i < KK * PXB; i += 256) pk[i] = b1[i >> 4];
    __syncthreads();

    // ---- conv1 3x3 SAME: 1 px + 8 channels per thread ----
    int px   = lane & 15;           // px within quarter
    int strm = t >> 4;              // c-stream 0..15 (bits 4,5 = in-wave)
    int pxg  = wq * 16 + px;        // global col

    float mt = (h > 0) ? 1.f : 0.f, mb = (h < HH - 1) ? 1.f : 0.f;
    float ml = (pxg > 0) ? 1.f : 0.f, mr = (pxg < WW - 1) ? 1.f : 0.f;
    int ya = (h > 0) ? h - 1 : 0;
    int yb = (h < HH - 1) ? h + 1 : HH - 1;
    int xl = (pxg > 0) ? pxg - 1 : 0;
    int xr = (pxg < WW - 1) ? pxg + 1 : WW - 1;

    float acc[KK];
    #pragma unroll
    for (int k = 0; k < KK; ++k) acc[k] = 0.f;

    const float* xb = x + (size_t)b * CC * (HH * WW);
    int cbase = strm * 8;
    const float* wb = w1tp + (size_t)cbase * 300;

    #pragma unroll 2
    for (int ci = 0; ci < 8; ++ci) {
        const float* xp = xb + (size_t)(cbase + ci) * (HH * WW);
        const float* r0 = xp + ya * WW;
        const float* r1 = xp + h  * WW;
        const float* r2 = xp + yb * WW;
        float x00 = r0[xl] * (mt * ml), x01 = r0[pxg] * mt, x02 = r0[xr] * (mt * mr);
        float x10 = r1[xl] * ml,        x11 = r1[pxg],      x12 = r1[xr] * mr;
        float x20 = r2[xl] * (mb * ml), x21 = r2[pxg] * mb, x22 = r2[xr] * (mb * mr);

        const float* wc = wb + ci * 300;
        #pragma unroll
        for (int kk = 0; kk < KK; ++kk) {
            float4 wA = *(const float4*)(wc + kk * 12);
            float4 wB = *(const float4*)(wc + kk * 12 + 4);
            float  w8 = wc[kk * 12 + 8];
            acc[kk] += x00 * wA.x + x01 * wA.y + x02 * wA.z
                     + x10 * wA.w + x11 * wB.x + x12 * wB.y
                     + x20 * wB.z + x21 * wB.w + x22 * w8;
        }
    }

    // butterfly over the 4 in-wave c-streams (lane bits 4,5)
    #pragma unroll
    for (int k = 0; k < KK; ++k) {
        acc[k] += __shfl_xor(acc[k], 16);
        acc[k] += __shfl_xor(acc[k], 32);
    }
    if ((lane >> 4) == 0) {         // 16 px lanes per wave, 4 waves merge
        #pragma unroll
        for (int k = 0; k < KK; ++k)
            atomicAdd(&pk[k * PXB + px], acc[k]);
    }
    __syncthreads();

    // ---- phase C: in-register softmax + attention straight from L2 ----
    // thread = (pp2 = t&7 -> px {2pp2, 2pp2+1}, cw = t>>3 -> 4 channels)
    int pp2 = t & 7, cw = t >> 3;

    float2 lg[KK];
    #pragma unroll
    for (int k = 0; k < KK; ++k) lg[k] = *(const float2*)&pk[k * PXB + 2 * pp2];
    float m0 = -1e30f, m1 = -1e30f;
    #pragma unroll
    for (int k = 0; k < KK; ++k) { m0 = fmaxf(m0, lg[k].x); m1 = fmaxf(m1, lg[k].y); }
    float s0 = 0.f, s1 = 0.f;
    #pragma unroll
    for (int k = 0; k < KK; ++k) {
        lg[k].x = __expf(lg[k].x - m0); s0 += lg[k].x;
        lg[k].y = __expf(lg[k].y - m1); s1 += lg[k].y;
    }
    float i0 = 1.f / s0, i1 = 1.f / s1;
    #pragma unroll
    for (int k = 0; k < KK; ++k) { lg[k].x *= i0; lg[k].y *= i1; }

    // window geometry: 5 rows x 3 float2 loads (even col offsets -> a
    // float2 is fully in-bounds or fully out -> single mask per pair)
    int colg = wq * 16 + 2 * pp2 - 2;
    int coff[3]; float cmask[3];
    #pragma unroll
    for (int j = 0; j < 3; ++j) {
        int cg = colg + 2 * j;
        cmask[j] = (cg >= 0 && cg <= WW - 2) ? 1.f : 0.f;
        coff[j]  = min(max(cg, 0), WW - 2);
    }
    int yoff[5]; float msk[15];
    #pragma unroll
    for (int di = 0; di < 5; ++di) {
        int y = h + di - 2;
        float rm = (y >= 0 && y < HH) ? 1.f : 0.f;
        yoff[di] = min(max(y, 0), HH - 1) * WW;
        #pragma unroll
        for (int j = 0; j < 3; ++j) msk[di * 3 + j] = rm * cmask[j];
    }

    #pragma unroll 2
    for (int i4 = 0; i4 < 4; ++i4) {
        int c = i4 * 32 + cw;
        const float* xc = xb + (size_t)c * (HH * WW);
        float2 xv[15];
        #pragma unroll
        for (int di = 0; di < 5; ++di)
            #pragma unroll
            for (int j = 0; j < 3; ++j) {
                float2 v = *(const float2*)(xc + yoff[di] + coff[j]);
                float mm = msk[di * 3 + j];
                xv[di * 3 + j] = make_float2(v.x * mm, v.y * mm);
            }
        float t0 = 0.f, t1 = 0.f;
        #pragma unroll
        for (int di = 0; di < 5; ++di) {
            float2 x01 = xv[di * 3 + 0];
            float2 x23 = xv[di * 3 + 1];
            float2 x45 = xv[di * 3 + 2];
            t0 += lg[di*5+0].x * x01.x + lg[di*5+1].x * x01.y
                + lg[di*5+2].x * x23.x + lg[di*5+3].x * x23.y
                + lg[di*5+4].x * x45.x;
            t1 += lg[di*5+0].y * x01.y + lg[di*5+1].y * x23.x
                + lg[di*5+2].y * x23.y + lg[di*5+3].y * x45.x
                + lg[di*5+4].y * x45.y;
        }
        sKT[(2 * pp2) * 136 + c]     = f32_to_bf16(t0);
        sKT[(2 * pp2 + 1) * 136 + c] = f32_to_bf16(t1);
    }
    __syncthreads();

    // ---- MFMA: C[o][px] = sum_c W2s[o][c] * s[c][px] ----
    int wv = __builtin_amdgcn_readfirstlane(t >> 6);   // 0..3
    int fpx = lane & 15, quad = lane >> 4;
    floatx4 am[2] = {{0.f,0.f,0.f,0.f},{0.f,0.f,0.f,0.f}};
    #pragma unroll
    for (int ks = 0; ks < 4; ++ks) {
        short8 bf  = *(const short8*)&sKT[fpx * 136 + ks*32 + quad*8];
        short8 af0 = *(const short8*)&w2o[(size_t)(32*wv      + fpx) * CC + ks*32 + quad*8];
        short8 af1 = *(const short8*)&w2o[(size_t)(32*wv + 16 + fpx) * CC + ks*32 + quad*8];
        am[0] = __builtin_amdgcn_mfma_f32_16x16x32_bf16(af0, bf, am[0], 0, 0, 0);
        am[1] = __builtin_amdgcn_mfma_f32_16x16x32_bf16(af1, bf, am[1], 0, 0, 0);
    }

    // ---- epilogue: D[row=quad*4+reg][col=fpx] + b2, 2x2-replicated write ----
    float* ob = out + (size_t)b * OUTC * (4 * HH * WW);
    int y0 = 2 * h;
    int pxo = wq * 16 + fpx;
    #pragma unroll
    for (int mt2 = 0; mt2 < 2; ++mt2) {
        #pragma unroll
        for (int reg = 0; reg < 4; ++reg) {
            int o = 32*wv + 16*mt2 + quad*4 + reg;
            float v = am[mt2][reg] + b2[o];
            float2 v2 = make_float2(v, v);
            float* r0p = ob + ((size_t)o * (2*HH) + y0) * (2*WW) + 2*pxo;
            *(float2*)(r0p)        = v2;
            *(float2*)(r0p + 2*WW) = v2;
        }
    }
}

// ---------------------------------------------------------------------------
extern "C" void kernel_launch(void* const* d_in, const int* in_sizes, int n_in,
                              void* d_out, int out_size, void* d_ws, size_t ws_size,
                              hipStream_t stream) {
    const float* x  = (const float*)d_in[0];
    const float* w1 = (const float*)d_in[1];
    const float* b1 = (const float*)d_in[2];
    const float* w2 = (const float*)d_in[3];
    const float* b2 = (const float*)d_in[4];
    float* out = (float*)d_out;

    unsigned short* w2o = (unsigned short*)d_ws;               // 32 KB
    float* w1tp = (float*)(w2o + (size_t)OUTC * CC);           // 153.6 KB

    prep_kernel<<<(16384 + 38400 + 255) / 256, 256, 0, stream>>>(w2, w1, w2o, w1tp);
    fused_kernel<<<BB * HH * 4, 256, 0, stream>>>(x, w1tp, w2o, b1, b2, out);
}